// Round 4
// baseline (1097.861 us; speedup 1.0000x reference)
//
#include <hip/hip_runtime.h>
#include <hip/hip_bf16.h>
#include <math.h>

#define NN 8192

typedef __attribute__((ext_vector_type(8))) short          bf16x8;
typedef __attribute__((ext_vector_type(8))) unsigned short u16x8;
typedef __attribute__((ext_vector_type(4))) unsigned int   u32x4;
typedef __attribute__((ext_vector_type(4))) float          f32x4;

__device__ __forceinline__ unsigned int f2bf(float f) {
    unsigned int u = __builtin_bit_cast(unsigned int, f);
    u += 0x7fffu + ((u >> 16) & 1u);   // RNE; exact zeros stay zero
    return u >> 16;
}

// ---------------------------------------------------------------------------
// Fused triangular converter, vectorized. One block per lower 128x128 tile
// (ti >= tj). A: straight fp32->bf16. B: transpose-convert via packed-u32 LDS
// (2 k's per word; the packed word IS the Bt output word -> no repack).
// ---------------------------------------------------------------------------
__global__ __launch_bounds__(256) void conv_fused(const float* __restrict__ A,
                                                  const float* __restrict__ B,
                                                  unsigned short* __restrict__ Ab,
                                                  unsigned short* __restrict__ Bt) {
    __shared__ unsigned int lds32[64 * 129];   // [k2][n], stride 129 -> bank +1/row

    const int q  = blockIdx.x;
    int ti = (int)((sqrtf(8.0f * (float)q + 1.0f) - 1.0f) * 0.5f);
    while ((ti + 1) * (ti + 2) / 2 <= q) ++ti;
    while (ti * (ti + 1) / 2 > q) --ti;
    const int tj = q - ti * (ti + 1) / 2;      // tj <= ti

    const int t   = threadIdx.x;
    const int rr0 = t >> 4;          // 0..15
    const int cc  = (t & 15) * 8;    // 0..120

    // ---- A tile: straight convert ----
    {
        const size_t r0 = (size_t)ti * 128, c0 = (size_t)tj * 128;
        #pragma unroll
        for (int p = 0; p < 8; ++p) {
            const int rr = p * 16 + rr0;
            const float* src = A + (r0 + rr) * NN + c0 + cc;
            const f32x4 v0 = *(const f32x4*)src;
            const f32x4 v1 = *(const f32x4*)(src + 4);
            u16x8 o;
            o[0]=(unsigned short)f2bf(v0[0]); o[1]=(unsigned short)f2bf(v0[1]);
            o[2]=(unsigned short)f2bf(v0[2]); o[3]=(unsigned short)f2bf(v0[3]);
            o[4]=(unsigned short)f2bf(v1[0]); o[5]=(unsigned short)f2bf(v1[1]);
            o[6]=(unsigned short)f2bf(v1[2]); o[7]=(unsigned short)f2bf(v1[3]);
            *(u16x8*)(Ab + (r0 + rr) * NN + c0 + cc) = o;
        }
    }

    // ---- B tile: pack 2 k-rows/u32 into LDS, read columns as u32x4 ----
    {
        const size_t k0 = (size_t)ti * 128, n0g = (size_t)tj * 128;
        #pragma unroll
        for (int p = 0; p < 4; ++p) {
            const int k2 = p * 16 + rr0;                 // 0..63 (k pair index)
            const float* r0p = B + (k0 + 2 * k2) * NN + n0g + cc;
            const float* r1p = r0p + NN;
            const f32x4 a0 = *(const f32x4*)r0p;
            const f32x4 a1 = *(const f32x4*)(r0p + 4);
            const f32x4 b0 = *(const f32x4*)r1p;
            const f32x4 b1 = *(const f32x4*)(r1p + 4);
            u32x4 w0, w1;
            #pragma unroll
            for (int j = 0; j < 4; ++j) {
                w0[j] = f2bf(a0[j]) | (f2bf(b0[j]) << 16);
                w1[j] = f2bf(a1[j]) | (f2bf(b1[j]) << 16);
            }
            *(u32x4*)&lds32[k2 * 129 + cc]     = w0;
            *(u32x4*)&lds32[k2 * 129 + cc + 4] = w1;
        }
        __syncthreads();
        #pragma unroll
        for (int p = 0; p < 8; ++p) {
            const int n = p * 16 + rr0;     // output row (n), 0..127
            const int c = t & 15;           // k-chunk of 8 k's
            u32x4 r;
            #pragma unroll
            for (int i = 0; i < 4; ++i) r[i] = lds32[(c * 4 + i) * 129 + n];
            *(u32x4*)(Bt + (n0g + n) * NN + k0 + c * 8) = r;
        }
    }
}

// ---------------------------------------------------------------------------
// Triangular bf16 GEMM, 3-slot counted-vmcnt pipeline.
// Tile 256(M) x 128(N), BK=64, 512 threads = 8 waves (4 wm x 2 wn).
// LDS 3 x (32KB A + 16KB B) = 144KB, 1 block/CU.
// Raw s_barrier + vmcnt(12): tile t's loads (issued iter t-2) are guaranteed
// landed while tiles t+1,t+2 stay in flight across barriers (never drain to 0).
// ---------------------------------------------------------------------------
__global__ __launch_bounds__(512) void tri_gemm(const unsigned short* __restrict__ Ab,
                                                const unsigned short* __restrict__ Bt,
                                                float* __restrict__ C) {
    // row-major over (I-row, J): swap low 3-bit fields so each XCD gets a
    // contiguous same-work J-chunk within one I-row (bijective, LPT-preserving)
    const unsigned wg  = blockIdx.x;
    const unsigned wgs = (wg & ~63u) | ((wg & 7u) << 3) | ((wg & 63u) >> 3);
    const int I = 31 - (int)(wgs >> 6);     // longest-K rows dispatch first
    const int J = (int)(wgs & 63u);
    const int t = threadIdx.x;

    if (J >= 2 * I + 2) {                   // fully-above-diagonal: zero-fill
        const f32x4 z = {0.f, 0.f, 0.f, 0.f};
        const size_t r0 = (size_t)I * 256;
        const int    c0 = J * 128;
        #pragma unroll
        for (int p = 0; p < 16; ++p) {
            const int rr = p * 16 + (t >> 5);
            const int cc2 = (t & 31) * 4;
            *(f32x4*)(C + (r0 + rr) * NN + c0 + cc2) = z;
        }
        return;
    }

    __shared__ alignas(16) short sA[3 * 256 * 64];   // 96 KB
    __shared__ alignas(16) short sB[3 * 128 * 64];   // 48 KB

    const int wave = t >> 6;
    const int lane = t & 63;
    const int wm   = wave >> 1, wn = wave & 1;
    const int lr   = lane & 15, lk = lane >> 4;

    f32x4 acc[4][4] = {};

    const size_t arow0 = (size_t)I * 256;
    const size_t brow0 = (size_t)J * 128;
    const int    k00   = J * 128;
    const int    nt    = 4 * I + 4 - 2 * J;   // >= 2 always

    auto stage = [&](int tt, int slot) {
        const int k0 = k00 + tt * 64;
        char* baseA = (char*)sA + slot * (256 * 64 * 2);
        char* baseB = (char*)sB + slot * (128 * 64 * 2);
        #pragma unroll
        for (int i = 0; i < 4; ++i) {
            const int off = i * 8192 + t * 16;          // bytes
            const int r   = off >> 7;                   // 128B rows
            const int ss  = ((off >> 4) & 7) ^ (r & 7); // inverse-swizzled src slot
            const unsigned short* ga = Ab + (arow0 + r) * NN + k0 + ss * 8;
            __builtin_amdgcn_global_load_lds(
                (const __attribute__((address_space(1))) void*)ga,
                (__attribute__((address_space(3))) void*)(baseA + off), 16, 0, 0);
        }
        #pragma unroll
        for (int i = 0; i < 2; ++i) {
            const int off = i * 8192 + t * 16;
            const int r   = off >> 7;
            const int ss  = ((off >> 4) & 7) ^ (r & 7);
            const unsigned short* gb = Bt + (brow0 + r) * NN + k0 + ss * 8;
            __builtin_amdgcn_global_load_lds(
                (const __attribute__((address_space(1))) void*)gb,
                (__attribute__((address_space(3))) void*)(baseB + off), 16, 0, 0);
        }
    };

    stage(0, 0);
    stage(1, 1);

    int slot = 0;
    for (int tt = 0; tt < nt; ++tt) {
        int s2 = slot + 2; if (s2 >= 3) s2 -= 3;
        if (tt + 2 < nt) stage(tt + 2, s2);

        if (tt + 2 < nt)      asm volatile("s_waitcnt vmcnt(12)" ::: "memory");
        else if (tt + 1 < nt) asm volatile("s_waitcnt vmcnt(6)" ::: "memory");
        else                  asm volatile("s_waitcnt vmcnt(0)" ::: "memory");
        asm volatile("s_barrier" ::: "memory");

        const char* tA = (const char*)sA + slot * (256 * 64 * 2);
        const char* tB = (const char*)sB + slot * (128 * 64 * 2);
        #pragma unroll
        for (int kk = 0; kk < 2; ++kk) {
            bf16x8 af[4], bfr[4];
            #pragma unroll
            for (int m = 0; m < 4; ++m) {
                const int r = wm * 64 + m * 16 + lr;
                const int s = (kk * 4 + lk) ^ (r & 7);
                af[m] = *(const bf16x8*)(tA + r * 128 + s * 16);
            }
            #pragma unroll
            for (int n = 0; n < 4; ++n) {
                const int r = wn * 64 + n * 16 + lr;
                const int s = (kk * 4 + lk) ^ (r & 7);
                bfr[n] = *(const bf16x8*)(tB + r * 128 + s * 16);
            }
            #pragma unroll
            for (int m = 0; m < 4; ++m)
                #pragma unroll
                for (int n = 0; n < 4; ++n)
                    acc[m][n] = __builtin_amdgcn_mfma_f32_16x16x32_bf16(
                        af[m], bfr[n], acc[m][n], 0, 0, 0);
        }
        asm volatile("s_barrier" ::: "memory");   // slot free: iter t+1 stages t+3 here
        slot = slot + 1; if (slot >= 3) slot -= 3;
    }

    // epilogue: D col = lane&15, row = (lane>>4)*4 + reg
    const size_t crow0 = (size_t)I * 256 + wm * 64;
    const int    ccol0 = J * 128 + wn * 64;
    #pragma unroll
    for (int m = 0; m < 4; ++m)
        #pragma unroll
        for (int n = 0; n < 4; ++n)
            #pragma unroll
            for (int q2 = 0; q2 < 4; ++q2) {
                const size_t row = crow0 + m * 16 + lk * 4 + q2;
                const int    col = ccol0 + n * 16 + lr;
                C[row * NN + col] = acc[m][n][q2];
            }
}

extern "C" void kernel_launch(void* const* d_in, const int* in_sizes, int n_in,
                              void* d_out, int out_size, void* d_ws, size_t ws_size,
                              hipStream_t stream) {
    const float* A = (const float*)d_in[0];
    const float* B = (const float*)d_in[1];
    float*       C = (float*)d_out;

    unsigned short* Ab  = (unsigned short*)d_ws;                 // 128 MB
    unsigned short* Btw = Ab + (size_t)NN * NN;                  // 128 MB

    const int ntiles = (NN / 128) * (NN / 128 + 1) / 2;          // 2080 lower tiles
    conv_fused<<<ntiles, 256, 0, stream>>>(A, B, Ab, Btw);
    tri_gemm<<<2048, 512, 0, stream>>>(Ab, Btw, C);
}

// Round 5
// 899.640 us; speedup vs baseline: 1.2203x; 1.2203x over previous
//
#include <hip/hip_runtime.h>
#include <hip/hip_bf16.h>
#include <math.h>

#define NN 8192
#define BM 128
#define BK 64

typedef __attribute__((ext_vector_type(8))) short          bf16x8;
typedef __attribute__((ext_vector_type(8))) unsigned short u16x8;
typedef __attribute__((ext_vector_type(4))) unsigned int   u32x4;
typedef __attribute__((ext_vector_type(4))) float          f32x4;

__device__ __forceinline__ unsigned int f2bf(float f) {
    unsigned int u = __builtin_bit_cast(unsigned int, f);
    u += 0x7fffu + ((u >> 16) & 1u);   // RNE; exact zeros stay zero
    return u >> 16;
}

// ---------------------------------------------------------------------------
// Fused triangular converter (unchanged from round 4 — passed, ~120us).
// One block per lower 128x128 tile (ti >= tj). A: straight fp32->bf16.
// B: transpose-convert via packed-u32 LDS (2 k's per word; packed word IS
// the Bt output word -> no repack).
// ---------------------------------------------------------------------------
__global__ __launch_bounds__(256) void conv_fused(const float* __restrict__ A,
                                                  const float* __restrict__ B,
                                                  unsigned short* __restrict__ Ab,
                                                  unsigned short* __restrict__ Bt) {
    __shared__ unsigned int lds32[64 * 129];   // [k2][n], stride 129 -> bank +1/row

    const int q  = blockIdx.x;
    int ti = (int)((sqrtf(8.0f * (float)q + 1.0f) - 1.0f) * 0.5f);
    while ((ti + 1) * (ti + 2) / 2 <= q) ++ti;
    while (ti * (ti + 1) / 2 > q) --ti;
    const int tj = q - ti * (ti + 1) / 2;      // tj <= ti

    const int t   = threadIdx.x;
    const int rr0 = t >> 4;          // 0..15
    const int cc  = (t & 15) * 8;    // 0..120

    // ---- A tile: straight convert ----
    {
        const size_t r0 = (size_t)ti * 128, c0 = (size_t)tj * 128;
        #pragma unroll
        for (int p = 0; p < 8; ++p) {
            const int rr = p * 16 + rr0;
            const float* src = A + (r0 + rr) * NN + c0 + cc;
            const f32x4 v0 = *(const f32x4*)src;
            const f32x4 v1 = *(const f32x4*)(src + 4);
            u16x8 o;
            o[0]=(unsigned short)f2bf(v0[0]); o[1]=(unsigned short)f2bf(v0[1]);
            o[2]=(unsigned short)f2bf(v0[2]); o[3]=(unsigned short)f2bf(v0[3]);
            o[4]=(unsigned short)f2bf(v1[0]); o[5]=(unsigned short)f2bf(v1[1]);
            o[6]=(unsigned short)f2bf(v1[2]); o[7]=(unsigned short)f2bf(v1[3]);
            *(u16x8*)(Ab + (r0 + rr) * NN + c0 + cc) = o;
        }
    }

    // ---- B tile: pack 2 k-rows/u32 into LDS, read columns as u32x4 ----
    {
        const size_t k0 = (size_t)ti * 128, n0g = (size_t)tj * 128;
        #pragma unroll
        for (int p = 0; p < 4; ++p) {
            const int k2 = p * 16 + rr0;                 // 0..63 (k pair index)
            const float* r0p = B + (k0 + 2 * k2) * NN + n0g + cc;
            const float* r1p = r0p + NN;
            const f32x4 a0 = *(const f32x4*)r0p;
            const f32x4 a1 = *(const f32x4*)(r0p + 4);
            const f32x4 b0 = *(const f32x4*)r1p;
            const f32x4 b1 = *(const f32x4*)(r1p + 4);
            u32x4 w0, w1;
            #pragma unroll
            for (int j = 0; j < 4; ++j) {
                w0[j] = f2bf(a0[j]) | (f2bf(b0[j]) << 16);
                w1[j] = f2bf(a1[j]) | (f2bf(b1[j]) << 16);
            }
            *(u32x4*)&lds32[k2 * 129 + cc]     = w0;
            *(u32x4*)&lds32[k2 * 129 + cc + 4] = w1;
        }
        __syncthreads();
        #pragma unroll
        for (int p = 0; p < 8; ++p) {
            const int n = p * 16 + rr0;     // output row (n), 0..127
            const int c = t & 15;           // k-chunk of 8 k's
            u32x4 r;
            #pragma unroll
            for (int i = 0; i < 4; ++i) r[i] = lds32[(c * 4 + i) * 129 + n];
            *(u32x4*)(Bt + (n0g + n) * NN + k0 + c * 8) = r;
        }
    }
}

// ---------------------------------------------------------------------------
// Triangular bf16 GEMM — r3 geometry (128^2, 4 waves, proven 0-conflict
// swizzle) + minimal 2-phase double-buffer with counted vmcnt (T3/T4) and
// setprio around MFMA (T5). LDS 64KB -> 2 blocks/CU co-resident.
// Loop invariant: at iter t's wait point, in-flight loads = 8 (tile t,
// issued iter t-1) + 8 (tile t+1, just issued); vmcnt(8) -> tile t landed,
// tile t+1 stays in flight across both barriers (never drains mid-loop).
// Buffer safety: tile t+1 lands in buf[cur^1], last read at iter t-1 whose
// end-barrier precedes this iter's stage issue.
// ---------------------------------------------------------------------------
__global__ __launch_bounds__(256) void tri_gemm(const unsigned short* __restrict__ Ab,
                                                const unsigned short* __restrict__ Bt,
                                                float* __restrict__ C) {
    const int bi = 63 - (int)blockIdx.y;     // long-K rows dispatch first (LPT)
    const int bj = (int)blockIdx.x;
    const int t  = threadIdx.x;

    if (bj > bi) {                           // upper-triangle tile: zero-fill
        const f32x4 z = {0.f, 0.f, 0.f, 0.f};
        const size_t r0 = (size_t)bi * BM;
        const int    c0 = bj * BM;
        #pragma unroll
        for (int p = 0; p < 16; ++p) {
            const int rr = p * 8 + (t >> 5);
            const int cc = (t & 31) * 4;
            *(f32x4*)(C + (r0 + rr) * NN + c0 + cc) = z;
        }
        return;
    }

    __shared__ alignas(16) unsigned short sA[2 * BM * BK];   // 32 KB (2 buf)
    __shared__ alignas(16) unsigned short sB[2 * BM * BK];   // 32 KB

    const int wave = t >> 6;
    const int lane = t & 63;
    const int wr   = wave >> 1, wc = wave & 1;   // 2x2 waves -> 64x64 out each
    const int lr   = lane & 15, lk = lane >> 4;

    f32x4 acc[4][4] = {};

    const size_t arow0 = (size_t)bi * BM;
    const size_t brow0 = (size_t)bj * BM;
    const int    k00   = bj * BM;
    const int    nt    = (bi - bj + 1) * (BM / BK);   // >= 2

    // 8 global_load_lds per thread per stage (4 A + 4 B), wave-uniform LDS dest
    auto stage = [&](int tt, int b) {
        const int k0 = k00 + tt * BK;
        #pragma unroll
        for (int i = 0; i < 4; ++i) {
            const int off = i * 4096 + t * 16;              // linear LDS byte offset
            const int r   = off >> 7;                       // tile row (128B rows)
            const int ss  = ((off >> 4) & 7) ^ (r & 7);     // inverse-swizzled src slot
            const unsigned short* ga = Ab + (arow0 + r) * NN + k0 + ss * 8;
            const unsigned short* gb = Bt + (brow0 + r) * NN + k0 + ss * 8;
            char* la = (char*)sA + b * 16384 + i * 4096 + wave * 1024;
            char* lb = (char*)sB + b * 16384 + i * 4096 + wave * 1024;
            __builtin_amdgcn_global_load_lds(
                (const __attribute__((address_space(1))) void*)ga,
                (__attribute__((address_space(3))) void*)la, 16, 0, 0);
            __builtin_amdgcn_global_load_lds(
                (const __attribute__((address_space(1))) void*)gb,
                (__attribute__((address_space(3))) void*)lb, 16, 0, 0);
        }
    };

    stage(0, 0);
    int cur = 0;
    for (int tt = 0; tt < nt; ++tt) {
        if (tt + 1 < nt) {
            stage(tt + 1, cur ^ 1);                         // prefetch next tile
            asm volatile("s_waitcnt vmcnt(8)" ::: "memory"); // tile t landed; t+1 in flight
        } else {
            asm volatile("s_waitcnt vmcnt(0)" ::: "memory"); // final drain
        }
        asm volatile("s_barrier" ::: "memory");

        const char* tA = (const char*)sA + cur * 16384;
        const char* tB = (const char*)sB + cur * 16384;
        #pragma unroll
        for (int kk = 0; kk < 2; ++kk) {
            bf16x8 af[4], bfr[4];
            #pragma unroll
            for (int m = 0; m < 4; ++m) {
                const int r = wr * 64 + m * 16 + lr;
                const int s = (kk * 4 + lk) ^ (r & 7);      // swizzled read
                af[m] = *(const bf16x8*)(tA + r * 128 + s * 16);
            }
            #pragma unroll
            for (int n = 0; n < 4; ++n) {
                const int r = wc * 64 + n * 16 + lr;
                const int s = (kk * 4 + lk) ^ (r & 7);
                bfr[n] = *(const bf16x8*)(tB + r * 128 + s * 16);
            }
            __builtin_amdgcn_s_setprio(1);
            #pragma unroll
            for (int m = 0; m < 4; ++m)
                #pragma unroll
                for (int n = 0; n < 4; ++n)
                    acc[m][n] = __builtin_amdgcn_mfma_f32_16x16x32_bf16(
                        af[m], bfr[n], acc[m][n], 0, 0, 0);
            __builtin_amdgcn_s_setprio(0);
        }
        asm volatile("s_barrier" ::: "memory");   // buf[cur] free for iter t+1's stage
        cur ^= 1;
    }

    // epilogue: D col = lane&15, row = (lane>>4)*4 + reg
    const size_t crow0 = (size_t)bi * BM + wr * 64;
    const int    ccol0 = bj * BM + wc * 64;
    #pragma unroll
    for (int m = 0; m < 4; ++m)
        #pragma unroll
        for (int n = 0; n < 4; ++n)
            #pragma unroll
            for (int q2 = 0; q2 < 4; ++q2) {
                const size_t row = crow0 + m * 16 + lk * 4 + q2;
                const int    col = ccol0 + n * 16 + lr;
                C[row * NN + col] = acc[m][n][q2];
            }
}

extern "C" void kernel_launch(void* const* d_in, const int* in_sizes, int n_in,
                              void* d_out, int out_size, void* d_ws, size_t ws_size,
                              hipStream_t stream) {
    const float* A = (const float*)d_in[0];
    const float* B = (const float*)d_in[1];
    float*       C = (float*)d_out;

    unsigned short* Ab  = (unsigned short*)d_ws;                 // 128 MB
    unsigned short* Btw = Ab + (size_t)NN * NN;                  // 128 MB

    const int ntiles = (NN / 128) * (NN / 128 + 1) / 2;          // 2080 lower tiles
    conv_fused<<<ntiles, 256, 0, stream>>>(A, B, Ab, Btw);
    tri_gemm<<<dim3(64, 64), 256, 0, stream>>>(Ab, Btw, C);
}